// Round 5
// baseline (313.608 us; speedup 1.0000x reference)
//
#include <hip/hip_runtime.h>

typedef unsigned short u16;
typedef unsigned int u32;
typedef __attribute__((ext_vector_type(8))) short short8;
typedef __attribute__((ext_vector_type(4))) float f32x4;
typedef __attribute__((ext_vector_type(16))) float f32x16;
typedef __attribute__((ext_vector_type(4))) unsigned u32x4;

// async global->LDS, 16B per lane; LDS dst = wave-uniform base + lane*16
#define ASYNC_CP16(gsrc, ldst) \
  __builtin_amdgcn_global_load_lds((__attribute__((address_space(1))) void*)(gsrc), \
                                   (__attribute__((address_space(3))) void*)(ldst), 16, 0, 0)

static __device__ __forceinline__ u16 f2bf(float f) {
  u32 u = __builtin_bit_cast(u32, f);
  u = u + 0x7fffu + ((u >> 16) & 1u);   // RNE
  return (u16)(u >> 16);
}
static __device__ __forceinline__ u32 pk2(float a, float b) {
  return (u32)f2bf(a) | ((u32)f2bf(b) << 16);
}
// single-instruction packed f32->2xbf16 (RNE)
static __device__ __forceinline__ u32 cvtpk(float lo, float hi) {
  u32 r;
  asm("v_cvt_pk_bf16_f32 %0, %1, %2" : "=v"(r) : "v"(lo), "v"(hi));
  return r;
}
// swap upper 32 lanes of a with lower 32 lanes of b
static __device__ __forceinline__ void plswap(u32 &a, u32 &b) {
  asm("v_permlane32_swap_b32 %0, %1" : "+v"(a), "+v"(b));
}

// ---------------------------------------------------------------------------
// Kernel 0: fp32 -> bf16 conversion into ws.
// ---------------------------------------------------------------------------
__global__ __launch_bounds__(256) void convert_all(
    const float* __restrict__ xq, const float* __restrict__ xkv,
    const float* __restrict__ wq, const float* __restrict__ wk,
    const float* __restrict__ wv, const float* __restrict__ wo,
    u16* __restrict__ dst)
{
  long i = ((long)blockIdx.x * 256 + threadIdx.x) * 4;
  const float* s; long o;
  if      (i < 8388608)  { s = xq;  o = i; }
  else if (i < 16777216) { s = xkv; o = i - 8388608; }
  else if (i < 17825792) { s = wq;  o = i - 16777216; }
  else if (i < 18874368) { s = wk;  o = i - 17825792; }
  else if (i < 19922944) { s = wv;  o = i - 18874368; }
  else                   { s = wo;  o = i - 19922944; }
  float4 v = *(const float4*)(s + o);
  uint2 pkv; pkv.x = pk2(v.x, v.y); pkv.y = pk2(v.z, v.w);
  *(uint2*)(dst + i) = pkv;
}

// ---------------------------------------------------------------------------
// QKV GEMM: 256x256 tile, BK=64, 8 waves (2x4), 4 quadrant phases per K-tile
// (T3), T2 XOR-swizzled LDS (verified: bank conflicts = 0), T5 setprio.
// v2 boundary (the m218 counted-vmcnt fix): at tile t's last phase, after the
// read-completion barrier, issue tile t+2's 8 loads into buf[cur] (freed:
// lgkmcnt(0) precedes the phase barrier, so all waves' reads landed), then
// vmcnt(8) waits only for tile t+1's loads (issued one full tile earlier).
// vmcnt never drains to 0 in the main loop. LDS = 128 KB -> 1 blk/CU.
// C[m][n] = sum_k A[m][k] * W[n][k] + bias[n]; z selects Q/K/V epilogue:
//   z=0: Q * (0.125*log2e), layout [bh][n][64]
//   z=1: K chunked  [bh][kt=n/128][dblk=d/8][key=n%128][8]   (8192 u16/tile)
//   z=2: V^T chunked [bh][kt][keyblk=(n%128)/8][d][8]        (8192 u16/tile)
// ---------------------------------------------------------------------------
__global__ __launch_bounds__(512, 2)
void gemm8(const u16* __restrict__ Axq, const u16* __restrict__ Axkv,
           const u16* __restrict__ W0, const u16* __restrict__ W1, const u16* __restrict__ W2,
           const float* __restrict__ b0, const float* __restrict__ b1, const float* __restrict__ b2,
           u16* __restrict__ Qo, u16* __restrict__ Ko, u16* __restrict__ Vo)
{
  // A bufs at u16 0 / 16384, B bufs at 32768 / 49152 (32 KB per tile buf)
  __shared__ u16 lds[65536];
  const int tid = threadIdx.x;
  const int w = tid >> 6, lane = tid & 63;
  const int wm = w >> 2, wn = w & 3;
  const int bm = blockIdx.x, bn = blockIdx.y, z = blockIdx.z;
  const int l15 = lane & 15, l4 = lane >> 4;

  const u16* A    = (z == 0) ? Axq : Axkv;
  const u16* W    = (z == 0) ? W0 : (z == 1) ? W1 : W2;
  const float* bias = (z == 0) ? b0 : (z == 1) ? b1 : b2;
  const u16* Ag = A + (long)bm*256*1024;
  const u16* Wg = W + (long)bn*256*1024;

  // staging offsets: thread covers LDS bytes (c*512+tid)*16 of each 16 KB
  // half-tile (h = row-half). Linear LDS dest; source k-chunk pre-swizzled
  // so LDS element (row, k) lives at chunk (k>>3)^(row&7).
  int srco[2][2], dsto[2][2];
#pragma unroll
  for (int h = 0; h < 2; ++h)
#pragma unroll
    for (int c = 0; c < 2; ++c) {
      const int rowl = (c*512 + tid) >> 3;       // row within half [0,128)
      const int kch  = (tid & 7) ^ (rowl & 7);   // source k-chunk
      srco[h][c] = (h*128 + rowl)*1024 + kch*8;  // u16 units
      dsto[h][c] = h*8192 + c*4096 + tid*8;      // u16 units within tile buf
    }

  f32x4 acc[8][4];
#pragma unroll
  for (int i = 0; i < 8; ++i)
#pragma unroll
    for (int j = 0; j < 4; ++j)
      acc[i][j] = (f32x4){0.f,0.f,0.f,0.f};

  // prologue: stage tiles 0 and 1; wait only for tile 0 (vmcnt(8))
#pragma unroll
  for (int h = 0; h < 2; ++h)
#pragma unroll
    for (int c = 0; c < 2; ++c) {
      ASYNC_CP16(Ag + srco[h][c], &lds[dsto[h][c]]);
      ASYNC_CP16(Wg + srco[h][c], &lds[32768 + dsto[h][c]]);
    }
#pragma unroll
  for (int h = 0; h < 2; ++h)
#pragma unroll
    for (int c = 0; c < 2; ++c) {
      ASYNC_CP16(Ag + srco[h][c] + 64, &lds[16384 + dsto[h][c]]);
      ASYNC_CP16(Wg + srco[h][c] + 64, &lds[49152 + dsto[h][c]]);
    }
  asm volatile("s_waitcnt vmcnt(8)" ::: "memory");
  __builtin_amdgcn_s_barrier();

  // swizzled ds_read chunk offsets for the two 32-k slices
  const int sx0 = ((l4)     ^ (l15 & 7)) * 8;    // u16 units
  const int sx1 = ((4 + l4) ^ (l15 & 7)) * 8;

  for (int t = 0; t < 16; ++t) {
    const int cur = t & 1;
    const u16* la = &lds[cur*16384];
    const u16* lb = &lds[32768 + cur*16384];

    // B-frags for the whole tile (8 ds_read_b128)
    short8 bfr[4][2];
#pragma unroll
    for (int fn = 0; fn < 4; ++fn) {
      const u16* rb = lb + (wn*64 + fn*16 + l15)*64;
      bfr[fn][0] = *(const short8*)(rb + sx0);
      bfr[fn][1] = *(const short8*)(rb + sx1);
    }

    // ---- 4 quadrant phases: q covers m-frags {2q, 2q+1} ----
#pragma unroll
    for (int q = 0; q < 4; ++q) {
      short8 af[2][2];
#pragma unroll
      for (int i = 0; i < 2; ++i) {
        const u16* ra = la + (wm*128 + (q*2 + i)*16 + l15)*64;
        af[i][0] = *(const short8*)(ra + sx0);
        af[i][1] = *(const short8*)(ra + sx1);
      }
      // own reads complete BEFORE the barrier: after it, buf[cur] reads are
      // done chip-wide (needed so q==3 can overwrite buf[cur] race-free)
      asm volatile("s_waitcnt lgkmcnt(0)" ::: "memory");
      __builtin_amdgcn_sched_barrier(0);
      __builtin_amdgcn_s_barrier();
      __builtin_amdgcn_s_setprio(1);
#pragma unroll
      for (int i = 0; i < 2; ++i)
#pragma unroll
        for (int fn = 0; fn < 4; ++fn) {
          acc[q*2+i][fn] = __builtin_amdgcn_mfma_f32_16x16x32_bf16(af[i][0], bfr[fn][0], acc[q*2+i][fn], 0, 0, 0);
          acc[q*2+i][fn] = __builtin_amdgcn_mfma_f32_16x16x32_bf16(af[i][1], bfr[fn][1], acc[q*2+i][fn], 0, 0, 0);
        }
      __builtin_amdgcn_s_setprio(0);
      __builtin_amdgcn_sched_barrier(0);
      if (q == 3) {
        if (t <= 13) {
          // issue tile t+2 into buf[cur] (its reads completed above)
          const int k0 = (t + 2)*64;
          u16* da = &lds[cur*16384];
          u16* db = &lds[32768 + cur*16384];
#pragma unroll
          for (int h = 0; h < 2; ++h)
#pragma unroll
            for (int c = 0; c < 2; ++c) {
              ASYNC_CP16(Ag + srco[h][c] + k0, da + dsto[h][c]);
              ASYNC_CP16(Wg + srco[h][c] + k0, db + dsto[h][c]);
            }
          // wait only for tile t+1 (issued one full tile ago); the 8 just-
          // issued loads stay in flight across the barrier (T4).
          asm volatile("s_waitcnt vmcnt(8)" ::: "memory");
        } else if (t == 14) {
          asm volatile("s_waitcnt vmcnt(0)" ::: "memory");  // tile 15 landed
        }
      }
      __builtin_amdgcn_s_barrier();
    }
  }

  // ---- epilogue: QKV scatter (unchanged logic, 8x4 frags) ----
#pragma unroll
  for (int fn = 0; fn < 4; ++fn) {
    const int colg = bn*256 + wn*64 + fn*16 + l15;
    const float bb = bias[colg];
#pragma unroll
    for (int fm = 0; fm < 8; ++fm) {
      const int rowg = bm*256 + wm*128 + fm*16 + l4*4;
      const int b  = rowg >> 11, n0 = rowg & 2047;
      const int h  = colg >> 6,  c  = colg & 63;
      const int bh = b*16 + h;
      const long hb = (long)bh*131072 + (long)(n0 >> 7)*8192;  // 8192 u16 per 128-key tile
      if (z == 0) {
        // scale = 0.125 * log2(e): softmax done in exp2 domain
#pragma unroll
        for (int r = 0; r < 4; ++r)
          Qo[((long)bh*2048 + n0 + r)*64 + c] = f2bf((acc[fm][fn][r] + bb) * 0.18033688f);
      } else if (z == 1) {
        const long base = hb + (long)(c >> 3)*1024 + (n0 & 127)*8 + (c & 7);
#pragma unroll
        for (int r = 0; r < 4; ++r)
          Ko[base + r*8] = f2bf(acc[fm][fn][r] + bb);
      } else {
        // n0 % 4 == 0 so rows n0..n0+3 stay inside one 8-key block
        const long base = hb + (long)((n0 & 127) >> 3)*512 + (long)c*8 + (n0 & 7);
        uint2 pkv;
        pkv.x = pk2(acc[fm][fn][0] + bb, acc[fm][fn][1] + bb);
        pkv.y = pk2(acc[fm][fn][2] + bb, acc[fm][fn][3] + bb);
        *(uint2*)(Vo + base) = pkv;
      }
    }
  }
}

// ---------------------------------------------------------------------------
// Output-projection GEMM (EPI=1 of the proven 128^2 dbuf structure):
// C = A @ Wo^T + bo, fp32 out. 512 WGs at 4 blk/CU.
// ---------------------------------------------------------------------------
__global__ __launch_bounds__(256)
void gemm_o(const u16* __restrict__ A, const u16* __restrict__ W,
            const float* __restrict__ bias, float* __restrict__ Fo)
{
  __shared__ u16 lsa[2][128*32];
  __shared__ u16 lsb[2][128*32];
  const int tid = threadIdx.x;
  const int w = tid >> 6, lane = tid & 63;
  const int wr = w >> 1, wc = w & 1;
  const int bm = blockIdx.x, bn = blockIdx.y;
  const int l15 = lane & 15, l4 = lane >> 4;

  const u16* Ag = A + (long)bm*128*1024;
  const u16* Wg = W + (long)bn*128*1024;

  f32x4 acc[4][4];
#pragma unroll
  for (int i = 0; i < 4; ++i)
#pragma unroll
    for (int j = 0; j < 4; ++j)
      acc[i][j] = (f32x4){0.f,0.f,0.f,0.f};

#pragma unroll
  for (int c = 0; c < 2; ++c) {
    int tp = c*256 + tid;
    int row = tp >> 2, col = (tp & 3) * 8;
    ASYNC_CP16(Ag + (long)row*1024 + col, &lsa[0][tp*8]);
    ASYNC_CP16(Wg + (long)row*1024 + col, &lsb[0][tp*8]);
  }

  for (int t = 0; t < 32; ++t) {
    const int cur = t & 1;
    if (t < 31) {
      const int k0 = (t + 1) * 32;
#pragma unroll
      for (int c = 0; c < 2; ++c) {
        int tp = c*256 + tid;
        int row = tp >> 2, col = (tp & 3) * 8;
        ASYNC_CP16(Ag + (long)row*1024 + k0 + col, &lsa[cur^1][tp*8]);
        ASYNC_CP16(Wg + (long)row*1024 + k0 + col, &lsb[cur^1][tp*8]);
      }
      asm volatile("s_waitcnt vmcnt(4)" ::: "memory");
    } else {
      asm volatile("s_waitcnt vmcnt(0)" ::: "memory");
    }
    __builtin_amdgcn_s_barrier();

    short8 af[4], bfr[4];
#pragma unroll
    for (int i = 0; i < 4; ++i)
      af[i] = *(const short8*)&lsa[cur][(wr*64 + i*16 + l15)*32 + l4*8];
#pragma unroll
    for (int j = 0; j < 4; ++j)
      bfr[j] = *(const short8*)&lsb[cur][(wc*64 + j*16 + l15)*32 + l4*8];
#pragma unroll
    for (int i = 0; i < 4; ++i)
#pragma unroll
      for (int j = 0; j < 4; ++j)
        acc[i][j] = __builtin_amdgcn_mfma_f32_16x16x32_bf16(af[i], bfr[j], acc[i][j], 0, 0, 0);

    asm volatile("" ::: "memory");
    __builtin_amdgcn_s_barrier();
  }

#pragma unroll
  for (int j = 0; j < 4; ++j) {
    const int colg = bn*128 + wc*64 + j*16 + l15;
    const float bb = bias[colg];
#pragma unroll
    for (int i = 0; i < 4; ++i) {
      const int rowg = bm*128 + wr*64 + i*16 + l4*4;
#pragma unroll
      for (int r = 0; r < 4; ++r)
        Fo[(long)(rowg + r)*1024 + colg] = acc[i][j][r] + bb;
    }
  }
}

// ---------------------------------------------------------------------------
// Flash attention v3: 32x32x16 MFMA core (2x LDS arithmetic intensity).
// 8 waves: wave w handles queries q0 + (w&3)*32 .. +31 against key-half
// (w>>2)*64 .. +63 of each 128-key tile. Per wave-iter: 8 QK MFMA + 8 PV
// MFMA, 16 KB LDS fragment reads. P stays in-register: cvt_pk_bf16 +
// v_permlane32_swap assemble the PV B-fragments (T12). Partial O/l of the
// two key-halves combined once in the epilogue through LDS. K/V double-
// buffered with counted vmcnt(4) across raw barriers. LDS = 64 KB.
// Causal, no online max (exp2-domain scores bounded; masked -> -1e30 -> 0).
// ---------------------------------------------------------------------------
__global__ __launch_bounds__(512, 4)
void attn_k(const u16* __restrict__ Q, const u16* __restrict__ K,
            const u16* __restrict__ V, u16* __restrict__ AO)
{
  __shared__ u16 lk[2][8192];     // K tile dbuf [dblk 8][key 128][8]
  __shared__ u16 lv[2][8192];     // V tile dbuf [keyblk 16][d 64][8]
  const int tid = threadIdx.x;
  const int w = tid >> 6, lane = tid & 63;
  const int l31 = lane & 31, l5 = lane >> 5;
  const int wq = w & 3, hh = w >> 2;
  const int qt = (gridDim.x - 1) - blockIdx.x;   // heavy blocks first
  const int bh = blockIdx.y;
  const int q0 = qt*128;
  const int qg = q0 + wq*32 + l31;               // this lane's query row
  const u16* Qh = Q + (long)bh*131072;
  const u16* Kh = K + (long)bh*131072;
  const u16* Vh = V + (long)bh*131072;

  // Q fragments: B-operand of 32x32x16, lane l: col=q (l&31), k=d=ks*16+l5*8+j
  short8 qf[4];
#pragma unroll
  for (int ks = 0; ks < 4; ++ks)
    qf[ks] = *(const short8*)&Qh[(long)qg*64 + ks*16 + l5*8];

  f32x16 o0 = (f32x16)0.0f;   // d 0-31   x q 0-31 (this wave's partial)
  f32x16 o1 = (f32x16)0.0f;   // d 32-63
  float rsum = 0.f;

  // per-lane LDS byte offsets within a tile
  const int koff = l5*2048 + l31*16;   // kf: dblk(l5 part) + key(l31)
  const int voff = l5*1024 + l31*16;   // vf: keyblk(l5 part) + d(l31)
  const int ktmax = qt;

  // prologue: stage tile 0 into buf 0 (4 cp16 per thread: K,V,K,V)
#pragma unroll
  for (int c = 0; c < 2; ++c) {
    int tp = c*512 + tid;
    ASYNC_CP16(Kh + tp*8, &lk[0][tp*8]);
    ASYNC_CP16(Vh + tp*8, &lv[0][tp*8]);
  }

  for (int kt = 0; kt <= ktmax; ++kt) {
    const int cur = kt & 1;
    if (kt < ktmax) {
      const long off = (long)(kt + 1)*8192;
#pragma unroll
      for (int c = 0; c < 2; ++c) {
        int tp = c*512 + tid;
        ASYNC_CP16(Kh + off + tp*8, &lk[cur^1][tp*8]);
        ASYNC_CP16(Vh + off + tp*8, &lv[cur^1][tp*8]);
      }
      asm volatile("s_waitcnt vmcnt(4)" ::: "memory");
    } else {
      asm volatile("s_waitcnt vmcnt(0)" ::: "memory");
    }
    __builtin_amdgcn_s_barrier();

    const char* lkc = (const char*)lk + cur*16384;
    const char* lvc = (const char*)lv + cur*16384;

    // diagonal tile: waves whose whole key-half exceeds their q range skip
    const bool active = !(kt == ktmax && hh*64 > wq*32 + 31);
    if (active) {
      short8 pf[4];   // PV B-fragments, key-slices (hh*4+j)*16..+15
#pragma unroll
      for (int sbl = 0; sbl < 2; ++sbl) {
        // S^T(32 keys x 32 q) = K . Q^T over d=64 (4 k-slices)
        f32x16 sa = (f32x16)0.0f;
#pragma unroll
        for (int ks = 0; ks < 4; ++ks) {
          short8 kf = *(const short8*)(lkc + koff + ks*4096 + (hh*2 + sbl)*512);
          sa = __builtin_amdgcn_mfma_f32_32x32x16_bf16(kf, qf[ks], sa, 0, 0, 0);
        }
        // causal mask (diagonal tile only); key = base + 8g + rr
        if (kt == ktmax) {
          const int kb = kt*128 + hh*64 + sbl*32 + 4*l5;
#pragma unroll
          for (int g = 0; g < 4; ++g)
#pragma unroll
            for (int rr = 0; rr < 4; ++rr)
              if (kb + 8*g + rr > qg) sa[4*g + rr] = -1e30f;
        }
        // p = exp2(s); per-lane l partial; pack to bf16 pairs
        float p[16];
#pragma unroll
        for (int r = 0; r < 16; ++r) p[r] = __builtin_amdgcn_exp2f(sa[r]);
#pragma unroll
        for (int g = 0; g < 4; ++g)
          rsum += (p[4*g] + p[4*g+1]) + (p[4*g+2] + p[4*g+3]);
        u32 cc[4][2];
#pragma unroll
        for (int g = 0; g < 4; ++g) {
          cc[g][0] = cvtpk(p[4*g],   p[4*g+1]);
          cc[g][1] = cvtpk(p[4*g+2], p[4*g+3]);
        }
        // cross-half exchange: one swap fills two output words
        plswap(cc[0][0], cc[1][0]); plswap(cc[0][1], cc[1][1]);
        plswap(cc[2][0], cc[3][0]); plswap(cc[2][1], cc[3][1]);
        u32x4 pw0 = {cc[0][0], cc[0][1], cc[1][0], cc[1][1]};
        u32x4 pw1 = {cc[2][0], cc[2][1], cc[3][0], cc[3][1]};
        pf[sbl*2]     = __builtin_bit_cast(short8, pw0);
        pf[sbl*2 + 1] = __builtin_bit_cast(short8, pw1);
      }
      // PV: o(d x q) += V^T . P over this wave's 64 keys (4 k-slices)
#pragma unroll
      for (int j = 0; j < 4; ++j) {
        const char* vb = lvc + voff + (hh*4 + j)*2048;
        short8 vf0 = *(const short8*)(vb);
        o0 = __builtin_amdgcn_mfma_f32_32x32x16_bf16(vf0, pf[j], o0, 0, 0, 0);
        short8 vf1 = *(const short8*)(vb + 512);
        o1 = __builtin_amdgcn_mfma_f32_32x32x16_bf16(vf1, pf[j], o1, 0, 0, 0);
      }
    }

    asm volatile("" ::: "memory");
    __builtin_amdgcn_s_barrier();
  }

  // ---- epilogue: combine the two key-half partials (waves w and w+4) ----
  __syncthreads();                       // all tile LDS ops done; reuse lk/lv
  float* exf = (float*)&lk[0][0];        // 32 KB: [wq 4][lane 64][32 f32]
  float* rxf = (float*)&lv[0][0];        // [wq 4][lane 64] l-partials
  const int sw = lane & 7;               // 16B-chunk swizzle
  float* xb = exf + wq*2048 + lane*32;

  if (hh == 1) {
#pragma unroll
    for (int c = 0; c < 4; ++c) {
      f32x4 v; v[0]=o0[c*4]; v[1]=o0[c*4+1]; v[2]=o0[c*4+2]; v[3]=o0[c*4+3];
      *(f32x4*)(xb + ((c ^ sw)*4)) = v;
    }
#pragma unroll
    for (int c = 0; c < 4; ++c) {
      f32x4 v; v[0]=o1[c*4]; v[1]=o1[c*4+1]; v[2]=o1[c*4+2]; v[3]=o1[c*4+3];
      *(f32x4*)(xb + (((c+4) ^ sw)*4)) = v;
    }
    rxf[wq*64 + lane] = rsum;
  }
  __syncthreads();
  if (hh == 0) {
    float rt = rsum + rxf[wq*64 + lane];
    rt += __shfl_xor(rt, 32, 64);
    const float inv = 1.0f / rt;
#pragma unroll
    for (int c = 0; c < 4; ++c) {
      f32x4 v = *(const f32x4*)(xb + ((c ^ sw)*4));
      o0[c*4] += v[0]; o0[c*4+1] += v[1]; o0[c*4+2] += v[2]; o0[c*4+3] += v[3];
    }
#pragma unroll
    for (int c = 0; c < 4; ++c) {
      f32x4 v = *(const f32x4*)(xb + (((c+4) ^ sw)*4));
      o1[c*4] += v[0]; o1[c*4+1] += v[1]; o1[c*4+2] += v[2]; o1[c*4+3] += v[3];
    }
    // write bf16 [tok][1024] (merged heads); d = dt*32 + 8g + 4*l5 + rr
    const int b = bh >> 4, h = bh & 15;
    const long tok = (long)b*2048 + qg;
    u16* dst = AO + tok*1024 + h*64;
#pragma unroll
    for (int g = 0; g < 4; ++g) {
      uint2 pkv;
      pkv.x = pk2(o0[4*g]*inv,   o0[4*g+1]*inv);
      pkv.y = pk2(o0[4*g+2]*inv, o0[4*g+3]*inv);
      *(uint2*)(dst + 8*g + 4*l5) = pkv;
    }
#pragma unroll
    for (int g = 0; g < 4; ++g) {
      uint2 pkv;
      pkv.x = pk2(o1[4*g]*inv,   o1[4*g+1]*inv);
      pkv.y = pk2(o1[4*g+2]*inv, o1[4*g+3]*inv);
      *(uint2*)(dst + 32 + 8*g + 4*l5) = pkv;
    }
  }
}

// ---------------------------------------------------------------------------
extern "C" void kernel_launch(void* const* d_in, const int* in_sizes, int n_in,
                              void* d_out, int out_size, void* d_ws, size_t ws_size,
                              hipStream_t stream)
{
  const float* xq  = (const float*)d_in[0];
  const float* xkv = (const float*)d_in[1];
  const float* Wq  = (const float*)d_in[2];
  const float* bq  = (const float*)d_in[3];
  const float* Wk  = (const float*)d_in[4];
  const float* bk  = (const float*)d_in[5];
  const float* Wv  = (const float*)d_in[6];
  const float* bv  = (const float*)d_in[7];
  const float* Wo  = (const float*)d_in[8];
  const float* bo  = (const float*)d_in[9];

  u16* ws    = (u16*)d_ws;
  u16* xq_b  = ws;                    // 8M bf16
  u16* xkv_b = xq_b  + (1l<<23);      // 8M
  u16* wq_b  = xkv_b + (1l<<23);      // 1M
  u16* wk_b  = wq_b  + (1l<<20);
  u16* wv_b  = wk_b  + (1l<<20);
  u16* wo_b  = wv_b  + (1l<<20);
  u16* Qb    = wo_b  + (1l<<20);      // 8M, [bh][n][64], scaled 0.125*log2e
  u16* Kb    = Qb    + (1l<<23);      // 8M, [bh][kt][dblk][key][8]
  u16* Vb    = Kb    + (1l<<23);      // 8M, [bh][kt][keyblk][d][8]
  u16* Ab    = Vb    + (1l<<23);      // 8M, [tok][1024]

  convert_all<<<20480, 256, 0, stream>>>(xq, xkv, Wq, Wk, Wv, Wo, ws);
  gemm8<<<dim3(32,4,3), 512, 0, stream>>>(xq_b, xkv_b, wq_b, wk_b, wv_b,
                                          bq, bk, bv, Qb, Kb, Vb);
  attn_k<<<dim3(16,64), 512, 0, stream>>>(Qb, Kb, Vb, Ab);
  gemm_o<<<dim3(64,8), 256, 0, stream>>>(Ab, wo_b, bo, (float*)d_out);
}

// Round 6
// 311.979 us; speedup vs baseline: 1.0052x; 1.0052x over previous
//
#include <hip/hip_runtime.h>

typedef unsigned short u16;
typedef unsigned int u32;
typedef __attribute__((ext_vector_type(8))) short short8;
typedef __attribute__((ext_vector_type(4))) float f32x4;
typedef __attribute__((ext_vector_type(16))) float f32x16;
typedef __attribute__((ext_vector_type(4))) unsigned u32x4;

// async global->LDS, 16B per lane; LDS dst = wave-uniform base + lane*16
#define ASYNC_CP16(gsrc, ldst) \
  __builtin_amdgcn_global_load_lds((__attribute__((address_space(1))) void*)(gsrc), \
                                   (__attribute__((address_space(3))) void*)(ldst), 16, 0, 0)

static __device__ __forceinline__ u16 f2bf(float f) {
  u32 u = __builtin_bit_cast(u32, f);
  u = u + 0x7fffu + ((u >> 16) & 1u);   // RNE
  return (u16)(u >> 16);
}
static __device__ __forceinline__ u32 pk2(float a, float b) {
  return (u32)f2bf(a) | ((u32)f2bf(b) << 16);
}
// single-instruction packed f32->2xbf16 (RNE)
static __device__ __forceinline__ u32 cvtpk(float lo, float hi) {
  u32 r;
  asm("v_cvt_pk_bf16_f32 %0, %1, %2" : "=v"(r) : "v"(lo), "v"(hi));
  return r;
}
// swap upper 32 lanes of a with lower 32 lanes of b
static __device__ __forceinline__ void plswap(u32 &a, u32 &b) {
  asm("v_permlane32_swap_b32 %0, %1" : "+v"(a), "+v"(b));
}

// ---------------------------------------------------------------------------
// Kernel 0: fp32 -> bf16 conversion into ws.
// ---------------------------------------------------------------------------
__global__ __launch_bounds__(256) void convert_all(
    const float* __restrict__ xq, const float* __restrict__ xkv,
    const float* __restrict__ wq, const float* __restrict__ wk,
    const float* __restrict__ wv, const float* __restrict__ wo,
    u16* __restrict__ dst)
{
  long i = ((long)blockIdx.x * 256 + threadIdx.x) * 4;
  const float* s; long o;
  if      (i < 8388608)  { s = xq;  o = i; }
  else if (i < 16777216) { s = xkv; o = i - 8388608; }
  else if (i < 17825792) { s = wq;  o = i - 16777216; }
  else if (i < 18874368) { s = wk;  o = i - 17825792; }
  else if (i < 19922944) { s = wv;  o = i - 18874368; }
  else                   { s = wo;  o = i - 19922944; }
  float4 v = *(const float4*)(s + o);
  uint2 pkv; pkv.x = pk2(v.x, v.y); pkv.y = pk2(v.z, v.w);
  *(uint2*)(dst + i) = pkv;
}

// ---------------------------------------------------------------------------
// QKV GEMM: 256x256 tile, BK=64, 8 waves (2x4), 4 quadrant phases per K-tile.
// T2 XOR-swizzled LDS (bank conflicts = 0, verified R4). T5 setprio.
// v3 schedule (the real m201 mechanism):
//  - software-pipelined ds_reads: phase q pre-reads phase q+1's A-frags
//    BEFORE its barrier+MFMA; the compiler emits counted lgkmcnt from
//    dataflow, so no phase ever exposes ds_read latency.
//  - one barrier per phase (lockstep), two at the tile boundary:
//    B1 (all waves' reads of buf[cur] drained, by MFMA dependence) ->
//    issue tile t+2's 8 loads into buf[cur] -> vmcnt(8) (waits only tile
//    t+1's loads, issued one tile earlier; the 8 new stay in flight) -> B2.
//    vmcnt never drains to 0 in steady state (T4).
// LDS = 128 KB -> 1 blk/CU. C[m][n] = sum_k A[m][k]*W[n][k] + bias[n].
// z selects Q/K/V epilogue:
//   z=0: Q * (0.125*log2e), layout [bh][n][64]
//   z=1: K chunked  [bh][kt=n/128][dblk=d/8][key=n%128][8]   (8192 u16/tile)
//   z=2: V^T chunked [bh][kt][keyblk=(n%128)/8][d][8]        (8192 u16/tile)
// ---------------------------------------------------------------------------
__global__ __launch_bounds__(512, 2)
void gemm8(const u16* __restrict__ Axq, const u16* __restrict__ Axkv,
           const u16* __restrict__ W0, const u16* __restrict__ W1, const u16* __restrict__ W2,
           const float* __restrict__ b0, const float* __restrict__ b1, const float* __restrict__ b2,
           u16* __restrict__ Qo, u16* __restrict__ Ko, u16* __restrict__ Vo)
{
  // A bufs at u16 0 / 16384, B bufs at 32768 / 49152 (32 KB per tile buf)
  __shared__ u16 lds[65536];
  const int tid = threadIdx.x;
  const int w = tid >> 6, lane = tid & 63;
  const int wm = w >> 2, wn = w & 3;
  const int bm = blockIdx.x, bn = blockIdx.y, z = blockIdx.z;
  const int l15 = lane & 15, l4 = lane >> 4;

  const u16* A    = (z == 0) ? Axq : Axkv;
  const u16* W    = (z == 0) ? W0 : (z == 1) ? W1 : W2;
  const float* bias = (z == 0) ? b0 : (z == 1) ? b1 : b2;
  const u16* Ag = A + (long)bm*256*1024;
  const u16* Wg = W + (long)bn*256*1024;

  // staging offsets: thread covers LDS bytes (c*512+tid)*16 of each 16 KB
  // half-tile (h = row-half). Linear LDS dest; source k-chunk pre-swizzled
  // so LDS element (row, k) lives at chunk (k>>3)^(row&7).
  int srco[2][2], dsto[2][2];
#pragma unroll
  for (int h = 0; h < 2; ++h)
#pragma unroll
    for (int c = 0; c < 2; ++c) {
      const int rowl = (c*512 + tid) >> 3;       // row within half [0,128)
      const int kch  = (tid & 7) ^ (rowl & 7);   // source k-chunk
      srco[h][c] = (h*128 + rowl)*1024 + kch*8;  // u16 units
      dsto[h][c] = h*8192 + c*4096 + tid*8;      // u16 units within tile buf
    }

  f32x4 acc[8][4];
#pragma unroll
  for (int i = 0; i < 8; ++i)
#pragma unroll
    for (int j = 0; j < 4; ++j)
      acc[i][j] = (f32x4){0.f,0.f,0.f,0.f};

  // prologue: stage tiles 0 and 1; wait only for tile 0 (vmcnt(8))
#pragma unroll
  for (int h = 0; h < 2; ++h)
#pragma unroll
    for (int c = 0; c < 2; ++c) {
      ASYNC_CP16(Ag + srco[h][c], &lds[dsto[h][c]]);
      ASYNC_CP16(Wg + srco[h][c], &lds[32768 + dsto[h][c]]);
    }
#pragma unroll
  for (int h = 0; h < 2; ++h)
#pragma unroll
    for (int c = 0; c < 2; ++c) {
      ASYNC_CP16(Ag + srco[h][c] + 64, &lds[16384 + dsto[h][c]]);
      ASYNC_CP16(Wg + srco[h][c] + 64, &lds[49152 + dsto[h][c]]);
    }
  asm volatile("s_waitcnt vmcnt(8)" ::: "memory");
  __builtin_amdgcn_s_barrier();

  // swizzled ds_read chunk offsets for the two 32-k slices
  const int sx0 = ((l4)     ^ (l15 & 7)) * 8;    // u16 units
  const int sx1 = ((4 + l4) ^ (l15 & 7)) * 8;

  for (int t = 0; t < 16; ++t) {
    const int cur = t & 1;
    const u16* la = &lds[cur*16384];
    const u16* lb = &lds[32768 + cur*16384];

    // tile-start reads: B-frags for the whole tile (8 b128) + phase-0 A (4)
    short8 bfr[4][2];
#pragma unroll
    for (int fn = 0; fn < 4; ++fn) {
      const u16* rb = lb + (wn*64 + fn*16 + l15)*64;
      bfr[fn][0] = *(const short8*)(rb + sx0);
      bfr[fn][1] = *(const short8*)(rb + sx1);
    }
    short8 afA[2][2], afB[2][2];
#pragma unroll
    for (int i = 0; i < 2; ++i) {
      const u16* ra = la + (wm*128 + i*16 + l15)*64;
      afA[i][0] = *(const short8*)(ra + sx0);
      afA[i][1] = *(const short8*)(ra + sx1);
    }

    // ---- 4 quadrant phases; phase q pre-reads phase q+1's A-frags so the
    // compiler's counted lgkm wait covers them under this phase's MFMA ----
#pragma unroll
    for (int q = 0; q < 4; ++q) {
      if (q < 3) {
#pragma unroll
        for (int i = 0; i < 2; ++i) {
          const u16* ra = la + (wm*128 + ((q + 1)*2 + i)*16 + l15)*64;
          afB[i][0] = *(const short8*)(ra + sx0);
          afB[i][1] = *(const short8*)(ra + sx1);
        }
      }
      __builtin_amdgcn_s_barrier();
      __builtin_amdgcn_s_setprio(1);
#pragma unroll
      for (int i = 0; i < 2; ++i)
#pragma unroll
        for (int fn = 0; fn < 4; ++fn) {
          acc[q*2+i][fn] = __builtin_amdgcn_mfma_f32_16x16x32_bf16(afA[i][0], bfr[fn][0], acc[q*2+i][fn], 0, 0, 0);
          acc[q*2+i][fn] = __builtin_amdgcn_mfma_f32_16x16x32_bf16(afA[i][1], bfr[fn][1], acc[q*2+i][fn], 0, 0, 0);
        }
      __builtin_amdgcn_s_setprio(0);
      // rotate the A-frag pipeline (compile-time indices; pure renames)
#pragma unroll
      for (int i = 0; i < 2; ++i) {
        afA[i][0] = afB[i][0];
        afA[i][1] = afB[i][1];
      }
    }

    // ---- tile boundary ----
    // B1: every wave's q=3 MFMA consumed its last ds_reads (compiler lgkm
    // dependence) => after this barrier no wave has reads of buf[cur] in
    // flight, so its DMA overwrite below is race-free.
    __builtin_amdgcn_s_barrier();
    if (t <= 13) {
      const int k0 = (t + 2)*64;
      u16* da = &lds[cur*16384];
      u16* db = &lds[32768 + cur*16384];
#pragma unroll
      for (int h = 0; h < 2; ++h)
#pragma unroll
        for (int c = 0; c < 2; ++c) {
          ASYNC_CP16(Ag + srco[h][c] + k0, da + dsto[h][c]);
          ASYNC_CP16(Wg + srco[h][c] + k0, db + dsto[h][c]);
        }
      // wait only for tile t+1 (issued one tile ago); the 8 just-issued
      // stay in flight across B2 (T4: vmcnt never 0 in steady state).
      asm volatile("s_waitcnt vmcnt(8)" ::: "memory");
    } else if (t == 14) {
      asm volatile("s_waitcnt vmcnt(0)" ::: "memory");  // tile 15 landed
    }
    // B2: all waves' share of tile t+1 landed -> safe to read next iter.
    __builtin_amdgcn_s_barrier();
  }

  // ---- epilogue: QKV scatter (unchanged logic, 8x4 frags) ----
#pragma unroll
  for (int fn = 0; fn < 4; ++fn) {
    const int colg = bn*256 + wn*64 + fn*16 + l15;
    const float bb = bias[colg];
#pragma unroll
    for (int fm = 0; fm < 8; ++fm) {
      const int rowg = bm*256 + wm*128 + fm*16 + l4*4;
      const int b  = rowg >> 11, n0 = rowg & 2047;
      const int h  = colg >> 6,  c  = colg & 63;
      const int bh = b*16 + h;
      const long hb = (long)bh*131072 + (long)(n0 >> 7)*8192;  // 8192 u16 per 128-key tile
      if (z == 0) {
        // scale = 0.125 * log2(e): softmax done in exp2 domain
#pragma unroll
        for (int r = 0; r < 4; ++r)
          Qo[((long)bh*2048 + n0 + r)*64 + c] = f2bf((acc[fm][fn][r] + bb) * 0.18033688f);
      } else if (z == 1) {
        const long base = hb + (long)(c >> 3)*1024 + (n0 & 127)*8 + (c & 7);
#pragma unroll
        for (int r = 0; r < 4; ++r)
          Ko[base + r*8] = f2bf(acc[fm][fn][r] + bb);
      } else {
        // n0 % 4 == 0 so rows n0..n0+3 stay inside one 8-key block
        const long base = hb + (long)((n0 & 127) >> 3)*512 + (long)c*8 + (n0 & 7);
        uint2 pkv;
        pkv.x = pk2(acc[fm][fn][0] + bb, acc[fm][fn][1] + bb);
        pkv.y = pk2(acc[fm][fn][2] + bb, acc[fm][fn][3] + bb);
        *(uint2*)(Vo + base) = pkv;
      }
    }
  }
}

// ---------------------------------------------------------------------------
// Output-projection GEMM (proven 128^2 dbuf structure):
// C = A @ Wo^T + bo, fp32 out. 512 WGs at 4 blk/CU.
// ---------------------------------------------------------------------------
__global__ __launch_bounds__(256)
void gemm_o(const u16* __restrict__ A, const u16* __restrict__ W,
            const float* __restrict__ bias, float* __restrict__ Fo)
{
  __shared__ u16 lsa[2][128*32];
  __shared__ u16 lsb[2][128*32];
  const int tid = threadIdx.x;
  const int w = tid >> 6, lane = tid & 63;
  const int wr = w >> 1, wc = w & 1;
  const int bm = blockIdx.x, bn = blockIdx.y;
  const int l15 = lane & 15, l4 = lane >> 4;

  const u16* Ag = A + (long)bm*128*1024;
  const u16* Wg = W + (long)bn*128*1024;

  f32x4 acc[4][4];
#pragma unroll
  for (int i = 0; i < 4; ++i)
#pragma unroll
    for (int j = 0; j < 4; ++j)
      acc[i][j] = (f32x4){0.f,0.f,0.f,0.f};

#pragma unroll
  for (int c = 0; c < 2; ++c) {
    int tp = c*256 + tid;
    int row = tp >> 2, col = (tp & 3) * 8;
    ASYNC_CP16(Ag + (long)row*1024 + col, &lsa[0][tp*8]);
    ASYNC_CP16(Wg + (long)row*1024 + col, &lsb[0][tp*8]);
  }

  for (int t = 0; t < 32; ++t) {
    const int cur = t & 1;
    if (t < 31) {
      const int k0 = (t + 1) * 32;
#pragma unroll
      for (int c = 0; c < 2; ++c) {
        int tp = c*256 + tid;
        int row = tp >> 2, col = (tp & 3) * 8;
        ASYNC_CP16(Ag + (long)row*1024 + k0 + col, &lsa[cur^1][tp*8]);
        ASYNC_CP16(Wg + (long)row*1024 + k0 + col, &lsb[cur^1][tp*8]);
      }
      asm volatile("s_waitcnt vmcnt(4)" ::: "memory");
    } else {
      asm volatile("s_waitcnt vmcnt(0)" ::: "memory");
    }
    __builtin_amdgcn_s_barrier();

    short8 af[4], bfr[4];
#pragma unroll
    for (int i = 0; i < 4; ++i)
      af[i] = *(const short8*)&lsa[cur][(wr*64 + i*16 + l15)*32 + l4*8];
#pragma unroll
    for (int j = 0; j < 4; ++j)
      bfr[j] = *(const short8*)&lsb[cur][(wc*64 + j*16 + l15)*32 + l4*8];
#pragma unroll
    for (int i = 0; i < 4; ++i)
#pragma unroll
      for (int j = 0; j < 4; ++j)
        acc[i][j] = __builtin_amdgcn_mfma_f32_16x16x32_bf16(af[i], bfr[j], acc[i][j], 0, 0, 0);

    asm volatile("" ::: "memory");
    __builtin_amdgcn_s_barrier();
  }

#pragma unroll
  for (int j = 0; j < 4; ++j) {
    const int colg = bn*128 + wc*64 + j*16 + l15;
    const float bb = bias[colg];
#pragma unroll
    for (int i = 0; i < 4; ++i) {
      const int rowg = bm*128 + wr*64 + i*16 + l4*4;
#pragma unroll
      for (int r = 0; r < 4; ++r)
        Fo[(long)(rowg + r)*1024 + colg] = acc[i][j][r] + bb;
    }
  }
}

// ---------------------------------------------------------------------------
// Flash attention v3: 32x32x16 MFMA core (2x LDS arithmetic intensity).
// 8 waves: wave w handles queries q0 + (w&3)*32 .. +31 against key-half
// (w>>2)*64 .. +63 of each 128-key tile. Per wave-iter: 8 QK MFMA + 8 PV
// MFMA, 16 KB LDS fragment reads. P stays in-register: cvt_pk_bf16 +
// v_permlane32_swap assemble the PV B-fragments (T12). Partial O/l of the
// two key-halves combined once in the epilogue through LDS. K/V double-
// buffered with counted vmcnt(4) across raw barriers. LDS = 64 KB.
// Causal, no online max (exp2-domain scores bounded; masked -> -1e30 -> 0).
// ---------------------------------------------------------------------------
__global__ __launch_bounds__(512, 4)
void attn_k(const u16* __restrict__ Q, const u16* __restrict__ K,
            const u16* __restrict__ V, u16* __restrict__ AO)
{
  __shared__ u16 lk[2][8192];     // K tile dbuf [dblk 8][key 128][8]
  __shared__ u16 lv[2][8192];     // V tile dbuf [keyblk 16][d 64][8]
  const int tid = threadIdx.x;
  const int w = tid >> 6, lane = tid & 63;
  const int l31 = lane & 31, l5 = lane >> 5;
  const int wq = w & 3, hh = w >> 2;
  const int qt = (gridDim.x - 1) - blockIdx.x;   // heavy blocks first
  const int bh = blockIdx.y;
  const int q0 = qt*128;
  const int qg = q0 + wq*32 + l31;               // this lane's query row
  const u16* Qh = Q + (long)bh*131072;
  const u16* Kh = K + (long)bh*131072;
  const u16* Vh = V + (long)bh*131072;

  // Q fragments: B-operand of 32x32x16, lane l: col=q (l&31), k=d=ks*16+l5*8+j
  short8 qf[4];
#pragma unroll
  for (int ks = 0; ks < 4; ++ks)
    qf[ks] = *(const short8*)&Qh[(long)qg*64 + ks*16 + l5*8];

  f32x16 o0 = (f32x16)0.0f;   // d 0-31   x q 0-31 (this wave's partial)
  f32x16 o1 = (f32x16)0.0f;   // d 32-63
  float rsum = 0.f;

  // per-lane LDS byte offsets within a tile
  const int koff = l5*2048 + l31*16;   // kf: dblk(l5 part) + key(l31)
  const int voff = l5*1024 + l31*16;   // vf: keyblk(l5 part) + d(l31)
  const int ktmax = qt;

  // prologue: stage tile 0 into buf 0 (4 cp16 per thread: K,V,K,V)
#pragma unroll
  for (int c = 0; c < 2; ++c) {
    int tp = c*512 + tid;
    ASYNC_CP16(Kh + tp*8, &lk[0][tp*8]);
    ASYNC_CP16(Vh + tp*8, &lv[0][tp*8]);
  }

  for (int kt = 0; kt <= ktmax; ++kt) {
    const int cur = kt & 1;
    if (kt < ktmax) {
      const long off = (long)(kt + 1)*8192;
#pragma unroll
      for (int c = 0; c < 2; ++c) {
        int tp = c*512 + tid;
        ASYNC_CP16(Kh + off + tp*8, &lk[cur^1][tp*8]);
        ASYNC_CP16(Vh + off + tp*8, &lv[cur^1][tp*8]);
      }
      asm volatile("s_waitcnt vmcnt(4)" ::: "memory");
    } else {
      asm volatile("s_waitcnt vmcnt(0)" ::: "memory");
    }
    __builtin_amdgcn_s_barrier();

    const char* lkc = (const char*)lk + cur*16384;
    const char* lvc = (const char*)lv + cur*16384;

    // diagonal tile: waves whose whole key-half exceeds their q range skip
    const bool active = !(kt == ktmax && hh*64 > wq*32 + 31);
    if (active) {
      short8 pf[4];   // PV B-fragments, key-slices (hh*4+j)*16..+15
#pragma unroll
      for (int sbl = 0; sbl < 2; ++sbl) {
        // S^T(32 keys x 32 q) = K . Q^T over d=64 (4 k-slices)
        f32x16 sa = (f32x16)0.0f;
#pragma unroll
        for (int ks = 0; ks < 4; ++ks) {
          short8 kf = *(const short8*)(lkc + koff + ks*4096 + (hh*2 + sbl)*512);
          sa = __builtin_amdgcn_mfma_f32_32x32x16_bf16(kf, qf[ks], sa, 0, 0, 0);
        }
        // causal mask (diagonal tile only); key = base + 8g + rr
        if (kt == ktmax) {
          const int kb = kt*128 + hh*64 + sbl*32 + 4*l5;
#pragma unroll
          for (int g = 0; g < 4; ++g)
#pragma unroll
            for (int rr = 0; rr < 4; ++rr)
              if (kb + 8*g + rr > qg) sa[4*g + rr] = -1e30f;
        }
        // p = exp2(s); per-lane l partial; pack to bf16 pairs
        float p[16];
#pragma unroll
        for (int r = 0; r < 16; ++r) p[r] = __builtin_amdgcn_exp2f(sa[r]);
#pragma unroll
        for (int g = 0; g < 4; ++g)
          rsum += (p[4*g] + p[4*g+1]) + (p[4*g+2] + p[4*g+3]);
        u32 cc[4][2];
#pragma unroll
        for (int g = 0; g < 4; ++g) {
          cc[g][0] = cvtpk(p[4*g],   p[4*g+1]);
          cc[g][1] = cvtpk(p[4*g+2], p[4*g+3]);
        }
        // cross-half exchange: one swap fills two output words
        plswap(cc[0][0], cc[1][0]); plswap(cc[0][1], cc[1][1]);
        plswap(cc[2][0], cc[3][0]); plswap(cc[2][1], cc[3][1]);
        u32x4 pw0 = {cc[0][0], cc[0][1], cc[1][0], cc[1][1]};
        u32x4 pw1 = {cc[2][0], cc[2][1], cc[3][0], cc[3][1]};
        pf[sbl*2]     = __builtin_bit_cast(short8, pw0);
        pf[sbl*2 + 1] = __builtin_bit_cast(short8, pw1);
      }
      // PV: o(d x q) += V^T . P over this wave's 64 keys (4 k-slices)
#pragma unroll
      for (int j = 0; j < 4; ++j) {
        const char* vb = lvc + voff + (hh*4 + j)*2048;
        short8 vf0 = *(const short8*)(vb);
        o0 = __builtin_amdgcn_mfma_f32_32x32x16_bf16(vf0, pf[j], o0, 0, 0, 0);
        short8 vf1 = *(const short8*)(vb + 512);
        o1 = __builtin_amdgcn_mfma_f32_32x32x16_bf16(vf1, pf[j], o1, 0, 0, 0);
      }
    }

    asm volatile("" ::: "memory");
    __builtin_amdgcn_s_barrier();
  }

  // ---- epilogue: combine the two key-half partials (waves w and w+4) ----
  __syncthreads();                       // all tile LDS ops done; reuse lk/lv
  float* exf = (float*)&lk[0][0];        // 32 KB: [wq 4][lane 64][32 f32]
  float* rxf = (float*)&lv[0][0];        // [wq 4][lane 64] l-partials
  const int sw = lane & 7;               // 16B-chunk swizzle
  float* xb = exf + wq*2048 + lane*32;

  if (hh == 1) {
#pragma unroll
    for (int c = 0; c < 4; ++c) {
      f32x4 v; v[0]=o0[c*4]; v[1]=o0[c*4+1]; v[2]=o0[c*4+2]; v[3]=o0[c*4+3];
      *(f32x4*)(xb + ((c ^ sw)*4)) = v;
    }
#pragma unroll
    for (int c = 0; c < 4; ++c) {
      f32x4 v; v[0]=o1[c*4]; v[1]=o1[c*4+1]; v[2]=o1[c*4+2]; v[3]=o1[c*4+3];
      *(f32x4*)(xb + (((c+4) ^ sw)*4)) = v;
    }
    rxf[wq*64 + lane] = rsum;
  }
  __syncthreads();
  if (hh == 0) {
    float rt = rsum + rxf[wq*64 + lane];
    rt += __shfl_xor(rt, 32, 64);
    const float inv = 1.0f / rt;
#pragma unroll
    for (int c = 0; c < 4; ++c) {
      f32x4 v = *(const f32x4*)(xb + ((c ^ sw)*4));
      o0[c*4] += v[0]; o0[c*4+1] += v[1]; o0[c*4+2] += v[2]; o0[c*4+3] += v[3];
    }
#pragma unroll
    for (int c = 0; c < 4; ++c) {
      f32x4 v = *(const f32x4*)(xb + (((c+4) ^ sw)*4));
      o1[c*4] += v[0]; o1[c*4+1] += v[1]; o1[c*4+2] += v[2]; o1[c*4+3] += v[3];
    }
    // write bf16 [tok][1024] (merged heads); d = dt*32 + 8g + 4*l5 + rr
    const int b = bh >> 4, h = bh & 15;
    const long tok = (long)b*2048 + qg;
    u16* dst = AO + tok*1024 + h*64;
#pragma unroll
    for (int g = 0; g < 4; ++g) {
      uint2 pkv;
      pkv.x = pk2(o0[4*g]*inv,   o0[4*g+1]*inv);
      pkv.y = pk2(o0[4*g+2]*inv, o0[4*g+3]*inv);
      *(uint2*)(dst + 8*g + 4*l5) = pkv;
    }
#pragma unroll
    for (int g = 0; g < 4; ++g) {
      uint2 pkv;
      pkv.x = pk2(o1[4*g]*inv,   o1[4*g+1]*inv);
      pkv.y = pk2(o1[4*g+2]*inv, o1[4*g+3]*inv);
      *(uint2*)(dst + 32 + 8*g + 4*l5) = pkv;
    }
  }
}

// ---------------------------------------------------------------------------
extern "C" void kernel_launch(void* const* d_in, const int* in_sizes, int n_in,
                              void* d_out, int out_size, void* d_ws, size_t ws_size,
                              hipStream_t stream)
{
  const float* xq  = (const float*)d_in[0];
  const float* xkv = (const float*)d_in[1];
  const float* Wq  = (const float*)d_in[2];
  const float* bq  = (const float*)d_in[3];
  const float* Wk  = (const float*)d_in[4];
  const float* bk  = (const float*)d_in[5];
  const float* Wv  = (const float*)d_in[6];
  const float* bv  = (const float*)d_in[7];
  const float* Wo  = (const float*)d_in[8];
  const float* bo  = (const float*)d_in[9];

  u16* ws    = (u16*)d_ws;
  u16* xq_b  = ws;                    // 8M bf16
  u16* xkv_b = xq_b  + (1l<<23);      // 8M
  u16* wq_b  = xkv_b + (1l<<23);      // 1M
  u16* wk_b  = wq_b  + (1l<<20);
  u16* wv_b  = wk_b  + (1l<<20);
  u16* wo_b  = wv_b  + (1l<<20);
  u16* Qb    = wo_b  + (1l<<20);      // 8M, [bh][n][64], scaled 0.125*log2e
  u16* Kb    = Qb    + (1l<<23);      // 8M, [bh][kt][dblk][key][8]
  u16* Vb    = Kb    + (1l<<23);      // 8M, [bh][kt][keyblk][d][8]
  u16* Ab    = Vb    + (1l<<23);      // 8M, [tok][1024]

  convert_all<<<20480, 256, 0, stream>>>(xq, xkv, Wq, Wk, Wv, Wo, ws);
  gemm8<<<dim3(32,4,3), 512, 0, stream>>>(xq_b, xkv_b, wq_b, wk_b, wv_b,
                                          bq, bk, bv, Qb, Kb, Vb);
  attn_k<<<dim3(16,64), 512, 0, stream>>>(Qb, Kb, Vb, Ab);
  gemm_o<<<dim3(64,8), 256, 0, stream>>>(Ab, wo_b, bo, (float*)d_out);
}

// Round 7
// 302.383 us; speedup vs baseline: 1.0371x; 1.0317x over previous
//
#include <hip/hip_runtime.h>

typedef unsigned short u16;
typedef unsigned int u32;
typedef __attribute__((ext_vector_type(8))) short short8;
typedef __attribute__((ext_vector_type(4))) float f32x4;
typedef __attribute__((ext_vector_type(16))) float f32x16;
typedef __attribute__((ext_vector_type(4))) unsigned u32x4;

// async global->LDS, 16B per lane; LDS dst = wave-uniform base + lane*16
#define ASYNC_CP16(gsrc, ldst) \
  __builtin_amdgcn_global_load_lds((__attribute__((address_space(1))) void*)(gsrc), \
                                   (__attribute__((address_space(3))) void*)(ldst), 16, 0, 0)

static __device__ __forceinline__ u16 f2bf(float f) {
  u32 u = __builtin_bit_cast(u32, f);
  u = u + 0x7fffu + ((u >> 16) & 1u);   // RNE
  return (u16)(u >> 16);
}
static __device__ __forceinline__ u32 pk2(float a, float b) {
  return (u32)f2bf(a) | ((u32)f2bf(b) << 16);
}
// single-instruction packed f32->2xbf16 (RNE)
static __device__ __forceinline__ u32 cvtpk(float lo, float hi) {
  u32 r;
  asm("v_cvt_pk_bf16_f32 %0, %1, %2" : "=v"(r) : "v"(lo), "v"(hi));
  return r;
}
// swap upper 32 lanes of a with lower 32 lanes of b
static __device__ __forceinline__ void plswap(u32 &a, u32 &b) {
  asm("v_permlane32_swap_b32 %0, %1" : "+v"(a), "+v"(b));
}

// ---------------------------------------------------------------------------
// Kernel 0: fp32 -> bf16 conversion into ws.
// ---------------------------------------------------------------------------
__global__ __launch_bounds__(256) void convert_all(
    const float* __restrict__ xq, const float* __restrict__ xkv,
    const float* __restrict__ wq, const float* __restrict__ wk,
    const float* __restrict__ wv, const float* __restrict__ wo,
    u16* __restrict__ dst)
{
  long i = ((long)blockIdx.x * 256 + threadIdx.x) * 4;
  const float* s; long o;
  if      (i < 8388608)  { s = xq;  o = i; }
  else if (i < 16777216) { s = xkv; o = i - 8388608; }
  else if (i < 17825792) { s = wq;  o = i - 16777216; }
  else if (i < 18874368) { s = wk;  o = i - 17825792; }
  else if (i < 19922944) { s = wv;  o = i - 18874368; }
  else                   { s = wo;  o = i - 19922944; }
  float4 v = *(const float4*)(s + o);
  uint2 pkv; pkv.x = pk2(v.x, v.y); pkv.y = pk2(v.z, v.w);
  *(uint2*)(dst + i) = pkv;
}

// ---------------------------------------------------------------------------
// Q projection: proven 128^2 dbuf structure, counted vmcnt(4).
// C = xq @ Wq^T + bq, scaled by 0.125*log2e, layout [bh][n][64].
// ---------------------------------------------------------------------------
__global__ __launch_bounds__(256)
void gemm_q(const u16* __restrict__ A, const u16* __restrict__ W,
            const float* __restrict__ bias, u16* __restrict__ Qo)
{
  __shared__ u16 lsa[2][128*32];
  __shared__ u16 lsb[2][128*32];
  const int tid = threadIdx.x;
  const int w = tid >> 6, lane = tid & 63;
  const int wr = w >> 1, wc = w & 1;
  const int bm = blockIdx.x, bn = blockIdx.y;
  const int l15 = lane & 15, l4 = lane >> 4;

  const u16* Ag = A + (long)bm*128*1024;
  const u16* Wg = W + (long)bn*128*1024;

  f32x4 acc[4][4];
#pragma unroll
  for (int i = 0; i < 4; ++i)
#pragma unroll
    for (int j = 0; j < 4; ++j)
      acc[i][j] = (f32x4){0.f,0.f,0.f,0.f};

#pragma unroll
  for (int c = 0; c < 2; ++c) {
    int tp = c*256 + tid;
    int row = tp >> 2, col = (tp & 3) * 8;
    ASYNC_CP16(Ag + (long)row*1024 + col, &lsa[0][tp*8]);
    ASYNC_CP16(Wg + (long)row*1024 + col, &lsb[0][tp*8]);
  }

  for (int t = 0; t < 32; ++t) {
    const int cur = t & 1;
    if (t < 31) {
      const int k0 = (t + 1) * 32;
#pragma unroll
      for (int c = 0; c < 2; ++c) {
        int tp = c*256 + tid;
        int row = tp >> 2, col = (tp & 3) * 8;
        ASYNC_CP16(Ag + (long)row*1024 + k0 + col, &lsa[cur^1][tp*8]);
        ASYNC_CP16(Wg + (long)row*1024 + k0 + col, &lsb[cur^1][tp*8]);
      }
      asm volatile("s_waitcnt vmcnt(4)" ::: "memory");
    } else {
      asm volatile("s_waitcnt vmcnt(0)" ::: "memory");
    }
    __builtin_amdgcn_s_barrier();

    short8 af[4], bfr[4];
#pragma unroll
    for (int i = 0; i < 4; ++i)
      af[i] = *(const short8*)&lsa[cur][(wr*64 + i*16 + l15)*32 + l4*8];
#pragma unroll
    for (int j = 0; j < 4; ++j)
      bfr[j] = *(const short8*)&lsb[cur][(wc*64 + j*16 + l15)*32 + l4*8];
#pragma unroll
    for (int i = 0; i < 4; ++i)
#pragma unroll
      for (int j = 0; j < 4; ++j)
        acc[i][j] = __builtin_amdgcn_mfma_f32_16x16x32_bf16(af[i], bfr[j], acc[i][j], 0, 0, 0);

    asm volatile("" ::: "memory");
    __builtin_amdgcn_s_barrier();
  }

#pragma unroll
  for (int j = 0; j < 4; ++j) {
    const int colg = bn*128 + wc*64 + j*16 + l15;
    const float bb = bias[colg];
    const int h = colg >> 6, c = colg & 63;
#pragma unroll
    for (int i = 0; i < 4; ++i) {
      const int rowg = bm*128 + wr*64 + i*16 + l4*4;
      const int b = rowg >> 11, n0 = rowg & 2047;
      const int bh = b*16 + h;
      // scale = 0.125 * log2(e): softmax done in exp2 domain
#pragma unroll
      for (int r = 0; r < 4; ++r)
        Qo[((long)bh*2048 + n0 + r)*64 + c] = f2bf((acc[i][j][r] + bb) * 0.18033688f);
    }
  }
}

// ---------------------------------------------------------------------------
// K+V fused projection: K and V share the SAME input matrix (xkv), so one
// block stages the A-tile ONCE against both Wk and Wv tiles. Staging per
// K-step: A 8 KB + Wk 8 KB + Wv 8 KB = 24 KB for 2x the FLOPs of a single
// 128^2 tile (85 vs 64 FLOP per staged byte, 1.33x intensity). All schedule
// variants converged at ~14 B/cyc/CU staging (R2-R6) -> intensity is the
// remaining lever. 4 waves, dual acc (128 VGPR), 2 blk/CU (gemm_o-like
// occupancy, the best measured per-CU staging config). dbuf, vmcnt(6).
// Epilogues = verified z=1 (K chunked) and z=2 (V^T chunked) scatter.
// ---------------------------------------------------------------------------
__global__ __launch_bounds__(256, 2)
void gemm_kv(const u16* __restrict__ A, const u16* __restrict__ Wk,
             const u16* __restrict__ Wv,
             const float* __restrict__ bkb, const float* __restrict__ bvb,
             u16* __restrict__ Ko, u16* __restrict__ Vo)
{
  __shared__ u16 lsa[2][128*32];
  __shared__ u16 lsk[2][128*32];
  __shared__ u16 lsv[2][128*32];
  const int tid = threadIdx.x;
  const int w = tid >> 6, lane = tid & 63;
  const int wr = w >> 1, wc = w & 1;
  const int bm = blockIdx.x, bn = blockIdx.y;
  const int l15 = lane & 15, l4 = lane >> 4;

  const u16* Ag = A  + (long)bm*128*1024;
  const u16* Kg = Wk + (long)bn*128*1024;
  const u16* Vg = Wv + (long)bn*128*1024;

  f32x4 ak[4][4], av[4][4];
#pragma unroll
  for (int i = 0; i < 4; ++i)
#pragma unroll
    for (int j = 0; j < 4; ++j) {
      ak[i][j] = (f32x4){0.f,0.f,0.f,0.f};
      av[i][j] = (f32x4){0.f,0.f,0.f,0.f};
    }

  // prologue: stage step 0 (6 cp16/thread: A,K,V x2)
#pragma unroll
  for (int c = 0; c < 2; ++c) {
    int tp = c*256 + tid;
    int row = tp >> 2, col = (tp & 3) * 8;
    ASYNC_CP16(Ag + (long)row*1024 + col, &lsa[0][tp*8]);
    ASYNC_CP16(Kg + (long)row*1024 + col, &lsk[0][tp*8]);
    ASYNC_CP16(Vg + (long)row*1024 + col, &lsv[0][tp*8]);
  }

  for (int t = 0; t < 32; ++t) {
    const int cur = t & 1;
    if (t < 31) {
      const int k0 = (t + 1) * 32;
#pragma unroll
      for (int c = 0; c < 2; ++c) {
        int tp = c*256 + tid;
        int row = tp >> 2, col = (tp & 3) * 8;
        ASYNC_CP16(Ag + (long)row*1024 + k0 + col, &lsa[cur^1][tp*8]);
        ASYNC_CP16(Kg + (long)row*1024 + k0 + col, &lsk[cur^1][tp*8]);
        ASYNC_CP16(Vg + (long)row*1024 + k0 + col, &lsv[cur^1][tp*8]);
      }
      // wait for the current step's 6 cps; the 6 just-issued stay in flight
      asm volatile("s_waitcnt vmcnt(6)" ::: "memory");
    } else {
      asm volatile("s_waitcnt vmcnt(0)" ::: "memory");
    }
    __builtin_amdgcn_s_barrier();

    short8 af[4], kf[4], vf[4];
#pragma unroll
    for (int i = 0; i < 4; ++i)
      af[i] = *(const short8*)&lsa[cur][(wr*64 + i*16 + l15)*32 + l4*8];
#pragma unroll
    for (int j = 0; j < 4; ++j) {
      kf[j] = *(const short8*)&lsk[cur][(wc*64 + j*16 + l15)*32 + l4*8];
      vf[j] = *(const short8*)&lsv[cur][(wc*64 + j*16 + l15)*32 + l4*8];
    }
#pragma unroll
    for (int i = 0; i < 4; ++i)
#pragma unroll
      for (int j = 0; j < 4; ++j) {
        ak[i][j] = __builtin_amdgcn_mfma_f32_16x16x32_bf16(af[i], kf[j], ak[i][j], 0, 0, 0);
        av[i][j] = __builtin_amdgcn_mfma_f32_16x16x32_bf16(af[i], vf[j], av[i][j], 0, 0, 0);
      }

    asm volatile("" ::: "memory");
    __builtin_amdgcn_s_barrier();
  }

  // ---- epilogue: K scatter (z=1 layout) + V scatter (z=2 layout) ----
#pragma unroll
  for (int j = 0; j < 4; ++j) {
    const int colg = bn*128 + wc*64 + j*16 + l15;
    const float kb = bkb[colg];
    const float vb = bvb[colg];
    const int h = colg >> 6, c = colg & 63;
#pragma unroll
    for (int i = 0; i < 4; ++i) {
      const int rowg = bm*128 + wr*64 + i*16 + l4*4;
      const int b = rowg >> 11, n0 = rowg & 2047;
      const int bh = b*16 + h;
      const long hb = (long)bh*131072 + (long)(n0 >> 7)*8192;  // 8192 u16 per 128-key tile
      // K chunked [bh][kt][dblk=c/8][key][8]
      const long kbase = hb + (long)(c >> 3)*1024 + (n0 & 127)*8 + (c & 7);
#pragma unroll
      for (int r = 0; r < 4; ++r)
        Ko[kbase + r*8] = f2bf(ak[i][j][r] + kb);
      // V^T chunked [bh][kt][keyblk][d][8]; n0 % 4 == 0 so rows n0..n0+3
      // stay inside one 8-key block
      const long vbase = hb + (long)((n0 & 127) >> 3)*512 + (long)c*8 + (n0 & 7);
      uint2 pkv;
      pkv.x = pk2(av[i][j][0] + vb, av[i][j][1] + vb);
      pkv.y = pk2(av[i][j][2] + vb, av[i][j][3] + vb);
      *(uint2*)(Vo + vbase) = pkv;
    }
  }
}

// ---------------------------------------------------------------------------
// Output-projection GEMM (proven 128^2 dbuf structure):
// C = A @ Wo^T + bo, fp32 out. 512 WGs.
// ---------------------------------------------------------------------------
__global__ __launch_bounds__(256)
void gemm_o(const u16* __restrict__ A, const u16* __restrict__ W,
            const float* __restrict__ bias, float* __restrict__ Fo)
{
  __shared__ u16 lsa[2][128*32];
  __shared__ u16 lsb[2][128*32];
  const int tid = threadIdx.x;
  const int w = tid >> 6, lane = tid & 63;
  const int wr = w >> 1, wc = w & 1;
  const int bm = blockIdx.x, bn = blockIdx.y;
  const int l15 = lane & 15, l4 = lane >> 4;

  const u16* Ag = A + (long)bm*128*1024;
  const u16* Wg = W + (long)bn*128*1024;

  f32x4 acc[4][4];
#pragma unroll
  for (int i = 0; i < 4; ++i)
#pragma unroll
    for (int j = 0; j < 4; ++j)
      acc[i][j] = (f32x4){0.f,0.f,0.f,0.f};

#pragma unroll
  for (int c = 0; c < 2; ++c) {
    int tp = c*256 + tid;
    int row = tp >> 2, col = (tp & 3) * 8;
    ASYNC_CP16(Ag + (long)row*1024 + col, &lsa[0][tp*8]);
    ASYNC_CP16(Wg + (long)row*1024 + col, &lsb[0][tp*8]);
  }

  for (int t = 0; t < 32; ++t) {
    const int cur = t & 1;
    if (t < 31) {
      const int k0 = (t + 1) * 32;
#pragma unroll
      for (int c = 0; c < 2; ++c) {
        int tp = c*256 + tid;
        int row = tp >> 2, col = (tp & 3) * 8;
        ASYNC_CP16(Ag + (long)row*1024 + k0 + col, &lsa[cur^1][tp*8]);
        ASYNC_CP16(Wg + (long)row*1024 + k0 + col, &lsb[cur^1][tp*8]);
      }
      asm volatile("s_waitcnt vmcnt(4)" ::: "memory");
    } else {
      asm volatile("s_waitcnt vmcnt(0)" ::: "memory");
    }
    __builtin_amdgcn_s_barrier();

    short8 af[4], bfr[4];
#pragma unroll
    for (int i = 0; i < 4; ++i)
      af[i] = *(const short8*)&lsa[cur][(wr*64 + i*16 + l15)*32 + l4*8];
#pragma unroll
    for (int j = 0; j < 4; ++j)
      bfr[j] = *(const short8*)&lsb[cur][(wc*64 + j*16 + l15)*32 + l4*8];
#pragma unroll
    for (int i = 0; i < 4; ++i)
#pragma unroll
      for (int j = 0; j < 4; ++j)
        acc[i][j] = __builtin_amdgcn_mfma_f32_16x16x32_bf16(af[i], bfr[j], acc[i][j], 0, 0, 0);

    asm volatile("" ::: "memory");
    __builtin_amdgcn_s_barrier();
  }

#pragma unroll
  for (int j = 0; j < 4; ++j) {
    const int colg = bn*128 + wc*64 + j*16 + l15;
    const float bb = bias[colg];
#pragma unroll
    for (int i = 0; i < 4; ++i) {
      const int rowg = bm*128 + wr*64 + i*16 + l4*4;
#pragma unroll
      for (int r = 0; r < 4; ++r)
        Fo[(long)(rowg + r)*1024 + colg] = acc[i][j][r] + bb;
    }
  }
}

// ---------------------------------------------------------------------------
// Flash attention v3: 32x32x16 MFMA core (2x LDS arithmetic intensity).
// 8 waves: wave w handles queries q0 + (w&3)*32 .. +31 against key-half
// (w>>2)*64 .. +63 of each 128-key tile. Per wave-iter: 8 QK MFMA + 8 PV
// MFMA, 16 KB LDS fragment reads. P stays in-register: cvt_pk_bf16 +
// v_permlane32_swap assemble the PV B-fragments (T12). Partial O/l of the
// two key-halves combined once in the epilogue through LDS. K/V double-
// buffered with counted vmcnt(4) across raw barriers. LDS = 64 KB.
// Causal, no online max (exp2-domain scores bounded; masked -> -1e30 -> 0).
// ---------------------------------------------------------------------------
__global__ __launch_bounds__(512, 4)
void attn_k(const u16* __restrict__ Q, const u16* __restrict__ K,
            const u16* __restrict__ V, u16* __restrict__ AO)
{
  __shared__ u16 lk[2][8192];     // K tile dbuf [dblk 8][key 128][8]
  __shared__ u16 lv[2][8192];     // V tile dbuf [keyblk 16][d 64][8]
  const int tid = threadIdx.x;
  const int w = tid >> 6, lane = tid & 63;
  const int l31 = lane & 31, l5 = lane >> 5;
  const int wq = w & 3, hh = w >> 2;
  const int qt = (gridDim.x - 1) - blockIdx.x;   // heavy blocks first
  const int bh = blockIdx.y;
  const int q0 = qt*128;
  const int qg = q0 + wq*32 + l31;               // this lane's query row
  const u16* Qh = Q + (long)bh*131072;
  const u16* Kh = K + (long)bh*131072;
  const u16* Vh = V + (long)bh*131072;

  // Q fragments: B-operand of 32x32x16, lane l: col=q (l&31), k=d=ks*16+l5*8+j
  short8 qf[4];
#pragma unroll
  for (int ks = 0; ks < 4; ++ks)
    qf[ks] = *(const short8*)&Qh[(long)qg*64 + ks*16 + l5*8];

  f32x16 o0 = (f32x16)0.0f;   // d 0-31   x q 0-31 (this wave's partial)
  f32x16 o1 = (f32x16)0.0f;   // d 32-63
  float rsum = 0.f;

  // per-lane LDS byte offsets within a tile
  const int koff = l5*2048 + l31*16;   // kf: dblk(l5 part) + key(l31)
  const int voff = l5*1024 + l31*16;   // vf: keyblk(l5 part) + d(l31)
  const int ktmax = qt;

  // prologue: stage tile 0 into buf 0 (4 cp16 per thread: K,V,K,V)
#pragma unroll
  for (int c = 0; c < 2; ++c) {
    int tp = c*512 + tid;
    ASYNC_CP16(Kh + tp*8, &lk[0][tp*8]);
    ASYNC_CP16(Vh + tp*8, &lv[0][tp*8]);
  }

  for (int kt = 0; kt <= ktmax; ++kt) {
    const int cur = kt & 1;
    if (kt < ktmax) {
      const long off = (long)(kt + 1)*8192;
#pragma unroll
      for (int c = 0; c < 2; ++c) {
        int tp = c*512 + tid;
        ASYNC_CP16(Kh + off + tp*8, &lk[cur^1][tp*8]);
        ASYNC_CP16(Vh + off + tp*8, &lv[cur^1][tp*8]);
      }
      asm volatile("s_waitcnt vmcnt(4)" ::: "memory");
    } else {
      asm volatile("s_waitcnt vmcnt(0)" ::: "memory");
    }
    __builtin_amdgcn_s_barrier();

    const char* lkc = (const char*)lk + cur*16384;
    const char* lvc = (const char*)lv + cur*16384;

    // diagonal tile: waves whose whole key-half exceeds their q range skip
    const bool active = !(kt == ktmax && hh*64 > wq*32 + 31);
    if (active) {
      short8 pf[4];   // PV B-fragments, key-slices (hh*4+j)*16..+15
#pragma unroll
      for (int sbl = 0; sbl < 2; ++sbl) {
        // S^T(32 keys x 32 q) = K . Q^T over d=64 (4 k-slices)
        f32x16 sa = (f32x16)0.0f;
#pragma unroll
        for (int ks = 0; ks < 4; ++ks) {
          short8 kf = *(const short8*)(lkc + koff + ks*4096 + (hh*2 + sbl)*512);
          sa = __builtin_amdgcn_mfma_f32_32x32x16_bf16(kf, qf[ks], sa, 0, 0, 0);
        }
        // causal mask (diagonal tile only); key = base + 8g + rr
        if (kt == ktmax) {
          const int kb = kt*128 + hh*64 + sbl*32 + 4*l5;
#pragma unroll
          for (int g = 0; g < 4; ++g)
#pragma unroll
            for (int rr = 0; rr < 4; ++rr)
              if (kb + 8*g + rr > qg) sa[4*g + rr] = -1e30f;
        }
        // p = exp2(s); per-lane l partial; pack to bf16 pairs
        float p[16];
#pragma unroll
        for (int r = 0; r < 16; ++r) p[r] = __builtin_amdgcn_exp2f(sa[r]);
#pragma unroll
        for (int g = 0; g < 4; ++g)
          rsum += (p[4*g] + p[4*g+1]) + (p[4*g+2] + p[4*g+3]);
        u32 cc[4][2];
#pragma unroll
        for (int g = 0; g < 4; ++g) {
          cc[g][0] = cvtpk(p[4*g],   p[4*g+1]);
          cc[g][1] = cvtpk(p[4*g+2], p[4*g+3]);
        }
        // cross-half exchange: one swap fills two output words
        plswap(cc[0][0], cc[1][0]); plswap(cc[0][1], cc[1][1]);
        plswap(cc[2][0], cc[3][0]); plswap(cc[2][1], cc[3][1]);
        u32x4 pw0 = {cc[0][0], cc[0][1], cc[1][0], cc[1][1]};
        u32x4 pw1 = {cc[2][0], cc[2][1], cc[3][0], cc[3][1]};
        pf[sbl*2]     = __builtin_bit_cast(short8, pw0);
        pf[sbl*2 + 1] = __builtin_bit_cast(short8, pw1);
      }
      // PV: o(d x q) += V^T . P over this wave's 64 keys (4 k-slices)
#pragma unroll
      for (int j = 0; j < 4; ++j) {
        const char* vb = lvc + voff + (hh*4 + j)*2048;
        short8 vf0 = *(const short8*)(vb);
        o0 = __builtin_amdgcn_mfma_f32_32x32x16_bf16(vf0, pf[j], o0, 0, 0, 0);
        short8 vf1 = *(const short8*)(vb + 512);
        o1 = __builtin_amdgcn_mfma_f32_32x32x16_bf16(vf1, pf[j], o1, 0, 0, 0);
      }
    }

    asm volatile("" ::: "memory");
    __builtin_amdgcn_s_barrier();
  }

  // ---- epilogue: combine the two key-half partials (waves w and w+4) ----
  __syncthreads();                       // all tile LDS ops done; reuse lk/lv
  float* exf = (float*)&lk[0][0];        // 32 KB: [wq 4][lane 64][32 f32]
  float* rxf = (float*)&lv[0][0];        // [wq 4][lane 64] l-partials
  const int sw = lane & 7;               // 16B-chunk swizzle
  float* xb = exf + wq*2048 + lane*32;

  if (hh == 1) {
#pragma unroll
    for (int c = 0; c < 4; ++c) {
      f32x4 v; v[0]=o0[c*4]; v[1]=o0[c*4+1]; v[2]=o0[c*4+2]; v[3]=o0[c*4+3];
      *(f32x4*)(xb + ((c ^ sw)*4)) = v;
    }
#pragma unroll
    for (int c = 0; c < 4; ++c) {
      f32x4 v; v[0]=o1[c*4]; v[1]=o1[c*4+1]; v[2]=o1[c*4+2]; v[3]=o1[c*4+3];
      *(f32x4*)(xb + (((c+4) ^ sw)*4)) = v;
    }
    rxf[wq*64 + lane] = rsum;
  }
  __syncthreads();
  if (hh == 0) {
    float rt = rsum + rxf[wq*64 + lane];
    rt += __shfl_xor(rt, 32, 64);
    const float inv = 1.0f / rt;
#pragma unroll
    for (int c = 0; c < 4; ++c) {
      f32x4 v = *(const f32x4*)(xb + ((c ^ sw)*4));
      o0[c*4] += v[0]; o0[c*4+1] += v[1]; o0[c*4+2] += v[2]; o0[c*4+3] += v[3];
    }
#pragma unroll
    for (int c = 0; c < 4; ++c) {
      f32x4 v = *(const f32x4*)(xb + (((c+4) ^ sw)*4));
      o1[c*4] += v[0]; o1[c*4+1] += v[1]; o1[c*4+2] += v[2]; o1[c*4+3] += v[3];
    }
    // write bf16 [tok][1024] (merged heads); d = dt*32 + 8g + 4*l5 + rr
    const int b = bh >> 4, h = bh & 15;
    const long tok = (long)b*2048 + qg;
    u16* dst = AO + tok*1024 + h*64;
#pragma unroll
    for (int g = 0; g < 4; ++g) {
      uint2 pkv;
      pkv.x = pk2(o0[4*g]*inv,   o0[4*g+1]*inv);
      pkv.y = pk2(o0[4*g+2]*inv, o0[4*g+3]*inv);
      *(uint2*)(dst + 8*g + 4*l5) = pkv;
    }
#pragma unroll
    for (int g = 0; g < 4; ++g) {
      uint2 pkv;
      pkv.x = pk2(o1[4*g]*inv,   o1[4*g+1]*inv);
      pkv.y = pk2(o1[4*g+2]*inv, o1[4*g+3]*inv);
      *(uint2*)(dst + 32 + 8*g + 4*l5) = pkv;
    }
  }
}

// ---------------------------------------------------------------------------
extern "C" void kernel_launch(void* const* d_in, const int* in_sizes, int n_in,
                              void* d_out, int out_size, void* d_ws, size_t ws_size,
                              hipStream_t stream)
{
  const float* xq  = (const float*)d_in[0];
  const float* xkv = (const float*)d_in[1];
  const float* Wq  = (const float*)d_in[2];
  const float* bq  = (const float*)d_in[3];
  const float* Wk  = (const float*)d_in[4];
  const float* bk  = (const float*)d_in[5];
  const float* Wv  = (const float*)d_in[6];
  const float* bv  = (const float*)d_in[7];
  const float* Wo  = (const float*)d_in[8];
  const float* bo  = (const float*)d_in[9];

  u16* ws    = (u16*)d_ws;
  u16* xq_b  = ws;                    // 8M bf16
  u16* xkv_b = xq_b  + (1l<<23);      // 8M
  u16* wq_b  = xkv_b + (1l<<23);      // 1M
  u16* wk_b  = wq_b  + (1l<<20);
  u16* wv_b  = wk_b  + (1l<<20);
  u16* wo_b  = wv_b  + (1l<<20);
  u16* Qb    = wo_b  + (1l<<20);      // 8M, [bh][n][64], scaled 0.125*log2e
  u16* Kb    = Qb    + (1l<<23);      // 8M, [bh][kt][dblk][key][8]
  u16* Vb    = Kb    + (1l<<23);      // 8M, [bh][kt][keyblk][d][8]
  u16* Ab    = Vb    + (1l<<23);      // 8M, [tok][1024]

  convert_all<<<20480, 256, 0, stream>>>(xq, xkv, Wq, Wk, Wv, Wo, ws);
  gemm_q<<<dim3(64,8), 256, 0, stream>>>(xq_b, wq_b, bq, Qb);
  gemm_kv<<<dim3(64,8), 256, 0, stream>>>(xkv_b, wk_b, wv_b, bk, bv, Kb, Vb);
  attn_k<<<dim3(16,64), 512, 0, stream>>>(Qb, Kb, Vb, Ab);
  gemm_o<<<dim3(64,8), 256, 0, stream>>>(Ab, wo_b, bo, (float*)d_out);
}